// Round 8
// baseline (79.265 us; speedup 1.0000x reference)
//
#include <hip/hip_runtime.h>

// Pointer-generator final distribution — chunk-per-block, LDS scatter,
// pure-streaming, full-occupancy, nontemporal-store version.
//
// out[b,t,v] = p*vocab[b,t,v] (v<V, 0 in pad) + scatter_add((1-p)*attn at ids)
//
// Grid = (NCHUNK=10, BT): each block owns one ~20 KB chunk of one row.
//   1) zero LDS chunk
//   2) scatter this row's (1-p)*attn hits landing in [lof,hif) into LDS
//      (LDS atomicAdd; duplicates accumulate, matching tf.scatter_nd)
//   3) barrier (block-start; 7 resident neighbor blocks cover it)
//   4) single uninterrupted stream: out = p*vocab + lds
//      (nt load AND nt store: out lines are never re-read -> L2
//       write-allocate is pure pollution vs the vocab read stream)
// No global RMW; every global access is a pure stream. 20048 B LDS ->
// 8 blocks/CU = 32 waves/CU, max occupancy.

typedef float float4v __attribute__((ext_vector_type(4)));

constexpr int TPB    = 256;
constexpr int CHUNK4 = 1253;        // float4s per chunk; 10*1253 >= Vext4
constexpr int CHUNKF = CHUNK4 * 4;  // 5012 floats = 20048 B LDS
constexpr int NCHUNK = 10;

__global__ __launch_bounds__(TPB) void pgn_chunk_lds_kernel(
    const float* __restrict__ vocab,   // [BT, V]
    const float* __restrict__ attn,    // [BT, L]
    const float* __restrict__ pg,      // [BT]
    const int* __restrict__ ids,       // [B, L]
    float* __restrict__ out,           // [BT, Vext]
    int T, int L, int V4, int Vext4) {
  __shared__ float lds[CHUNKF];
  float4v* lds4 = reinterpret_cast<float4v*>(lds);

  const int chunk = blockIdx.x;        // 0..NCHUNK-1
  const int row   = blockIdx.y;        // 0..B*T-1
  const int tid   = threadIdx.x;

  const int lo4 = chunk * CHUNK4;
  const int hi4 = min(lo4 + CHUNK4, Vext4);
  const int lof = lo4 * 4, hif = hi4 * 4;

  const float p = pg[row];
  const float q = 1.0f - p;
  const int b = row / T;               // scalar once per block

  // 1) zero the LDS chunk (~5 ds_write_b128 iters/thread).
  for (int c = tid; c < CHUNK4; c += TPB) lds4[c] = (float4v)(0.f);
  __syncthreads();

  // 2) scatter this row's hits that land in this chunk (~L/NCHUNK of L=400).
  const float* __restrict__ arow = attn + (long)row * L;
  const int* __restrict__ irow = ids + (long)b * L;
  for (int l = tid; l < L; l += TPB) {
    const int id = irow[l];
    if (id >= lof && id < hif) atomicAdd(lds + (id - lof), q * arow[l]);
  }
  __syncthreads();

  // 3+4) one uninterrupted ~20 KB stream. Consecutive float4/lane: LDS reads
  // 2-way bank-aliased (free), global fully coalesced.
  const float4v* __restrict__ vrow =
      reinterpret_cast<const float4v*>(vocab) + (long)row * V4;
  float4v* __restrict__ orow =
      reinterpret_cast<float4v*>(out) + (long)row * Vext4;
  for (int c4 = lo4 + tid; c4 < hi4; c4 += TPB) {
    float4v o = lds4[c4 - lo4];
    if (c4 < V4) o += p * __builtin_nontemporal_load(vrow + c4);
    __builtin_nontemporal_store(o, orow + c4);  // A/B vs R7: nt store
  }
}

extern "C" void kernel_launch(void* const* d_in, const int* in_sizes, int n_in,
                              void* d_out, int out_size, void* d_ws, size_t ws_size,
                              hipStream_t stream) {
  const float* vocab = (const float*)d_in[0];   // [B,T,V]
  const float* attn  = (const float*)d_in[1];   // [B,T,L]
  const float* pg    = (const float*)d_in[2];   // [B,T,1]
  const int*   ids   = (const int*)d_in[3];     // [B,L]
  float* out = (float*)d_out;

  const int BT   = in_sizes[2];            // B*T = 1024
  const int V    = in_sizes[0] / BT;       // 50000
  const int L    = in_sizes[1] / BT;       // 400
  const int Vext = out_size / BT;          // 50100
  const int B    = in_sizes[3] / L;        // 16
  const int T    = BT / B;                 // 64

  const int V4 = V / 4, Vext4 = Vext / 4;  // 12500, 12525 (rows 16B-aligned)

  dim3 grid(NCHUNK, BT);
  pgn_chunk_lds_kernel<<<grid, TPB, 0, stream>>>(vocab, attn, pg, ids, out,
                                                 T, L, V4, Vext4);
}

// Round 9
// 71.826 us; speedup vs baseline: 1.1036x; 1.1036x over previous
//
#include <hip/hip_runtime.h>

// Pointer-generator final distribution — chunk-per-block, LDS scatter,
// pure-streaming, full-occupancy version. FINAL (R7 config, best measured:
// 71.8 us ≈ 5.7 TB/s effective ≈ 91% of achievable mixed-stream BW).
//
// out[b,t,v] = p*vocab[b,t,v] (v<V, 0 in pad) + scatter_add((1-p)*attn at ids)
//
// Grid = (NCHUNK=10, BT): each block owns one ~20 KB chunk of one row.
//   1) zero LDS chunk
//   2) scatter this row's (1-p)*attn hits landing in [lof,hif) into LDS
//      (LDS atomicAdd; duplicates accumulate, matching tf.scatter_nd)
//   3) barrier (block-start; 7 resident neighbor blocks cover it)
//   4) single uninterrupted stream: out = p*vocab + lds  (nt vocab load,
//      NORMAL store — nt store A/B'd at -10% in R8)
// No global RMW; every global access is a pure stream. 20048 B LDS ->
// 8 blocks/CU = 32 waves/CU, max occupancy.
//
// A/B history: fusion + (R1->R3 104.8->81.3), LDS scatter + (R6),
// mid-stream barriers - (R5 102.1), chunk occupancy + (R7 77.2->71.8),
// nt loads + , nt stores - (R8 79.3).

typedef float float4v __attribute__((ext_vector_type(4)));

constexpr int TPB    = 256;
constexpr int CHUNK4 = 1253;        // float4s per chunk; 10*1253 >= Vext4
constexpr int CHUNKF = CHUNK4 * 4;  // 5012 floats = 20048 B LDS
constexpr int NCHUNK = 10;

__global__ __launch_bounds__(TPB) void pgn_chunk_lds_kernel(
    const float* __restrict__ vocab,   // [BT, V]
    const float* __restrict__ attn,    // [BT, L]
    const float* __restrict__ pg,      // [BT]
    const int* __restrict__ ids,       // [B, L]
    float* __restrict__ out,           // [BT, Vext]
    int T, int L, int V4, int Vext4) {
  __shared__ float lds[CHUNKF];
  float4v* lds4 = reinterpret_cast<float4v*>(lds);

  const int chunk = blockIdx.x;        // 0..NCHUNK-1
  const int row   = blockIdx.y;        // 0..B*T-1
  const int tid   = threadIdx.x;

  const int lo4 = chunk * CHUNK4;
  const int hi4 = min(lo4 + CHUNK4, Vext4);
  const int lof = lo4 * 4, hif = hi4 * 4;

  const float p = pg[row];
  const float q = 1.0f - p;
  const int b = row / T;               // scalar once per block

  // 1) zero the LDS chunk (~5 ds_write_b128 iters/thread).
  for (int c = tid; c < CHUNK4; c += TPB) lds4[c] = (float4v)(0.f);
  __syncthreads();

  // 2) scatter this row's hits that land in this chunk (~L/NCHUNK of L=400).
  const float* __restrict__ arow = attn + (long)row * L;
  const int* __restrict__ irow = ids + (long)b * L;
  for (int l = tid; l < L; l += TPB) {
    const int id = irow[l];
    if (id >= lof && id < hif) atomicAdd(lds + (id - lof), q * arow[l]);
  }
  __syncthreads();

  // 3+4) one uninterrupted ~20 KB stream. Consecutive float4/lane: LDS reads
  // 2-way bank-aliased (free), global fully coalesced.
  const float4v* __restrict__ vrow =
      reinterpret_cast<const float4v*>(vocab) + (long)row * V4;
  float4v* __restrict__ orow =
      reinterpret_cast<float4v*>(out) + (long)row * Vext4;
  for (int c4 = lo4 + tid; c4 < hi4; c4 += TPB) {
    float4v o = lds4[c4 - lo4];
    if (c4 < V4) o += p * __builtin_nontemporal_load(vrow + c4);
    orow[c4] = o;   // normal store (nt store regressed: R8)
  }
}

extern "C" void kernel_launch(void* const* d_in, const int* in_sizes, int n_in,
                              void* d_out, int out_size, void* d_ws, size_t ws_size,
                              hipStream_t stream) {
  const float* vocab = (const float*)d_in[0];   // [B,T,V]
  const float* attn  = (const float*)d_in[1];   // [B,T,L]
  const float* pg    = (const float*)d_in[2];   // [B,T,1]
  const int*   ids   = (const int*)d_in[3];     // [B,L]
  float* out = (float*)d_out;

  const int BT   = in_sizes[2];            // B*T = 1024
  const int V    = in_sizes[0] / BT;       // 50000
  const int L    = in_sizes[1] / BT;       // 400
  const int Vext = out_size / BT;          // 50100
  const int B    = in_sizes[3] / L;        // 16
  const int T    = BT / B;                 // 64

  const int V4 = V / 4, Vext4 = Vext / 4;  // 12500, 12525 (rows 16B-aligned)

  dim3 grid(NCHUNK, BT);
  pgn_chunk_lds_kernel<<<grid, TPB, 0, stream>>>(vocab, attn, pg, ids, out,
                                                 T, L, V4, Vext4);
}